// Round 1
// 213.312 us; speedup vs baseline: 1.6063x; 1.6063x over previous
//
#include <hip/hip_runtime.h>
#include <math.h>

// out[b,g, off+v*d+i] = 1/sqrt(128d) * sum_{f,u} x[b,f,off+u*d+i] * psi[f,g,off+u*d+v]
// psi[f,g,c'] = 1/sqrt(512) * sum_n D[n,c'] * w[f,g,n]
//
// Phase 1 (fused): single GEMM M=16384(f,g), N=512(all-l columns, u-fastest), K=512.
//   scatter-epilogue -> PSI_T[l][g*d+v][f*d+u] (bf16, K-major), runs of 2d bytes.
//   Fallback (small ws): per-l psi_gemm (previous verified kernel).
// Phase 2: per l: operand-swapped GEMM  M=128d (g,v) [A=PSI_T], N=256d (b,i) [B=XP2],
//   K=128d (f,u). Lane-fast N dim = i -> out stores are contiguous d-float runs in the
//   TRUE output layout (no fixup pass, no per-i batching).

typedef float f32x4 __attribute__((ext_vector_type(4)));
typedef short short8 __attribute__((ext_vector_type(8)));
typedef short short4v __attribute__((ext_vector_type(4)));
typedef __bf16 bf8 __attribute__((ext_vector_type(8)));

static __device__ inline bf8 as_bf8(short8 s) {
    union { short8 s; bf8 b; } u; u.s = s; return u.b;
}
static __device__ inline short f2bf(float f) {
    union { float f; unsigned u; } v; v.f = f;
    unsigned r = v.u + 0x7FFFu + ((v.u >> 16) & 1u);   // RNE
    return (short)(r >> 16);
}

static const int OFFS_H[8] = {0, 1, 10, 35, 84, 165, 286, 455};
static const size_t PSIOFF_H[7] = {0, 16384, 163840, 573440, 1376256, 2703360, 4685824};
__constant__ int OFFS_D[8] = {0, 1, 10, 35, 84, 165, 286, 455};
__constant__ unsigned PSIOFF_D[7] = {0, 16384, 163840, 573440, 1376256, 2703360, 4685824};

// ---------------- D transpose + bf16: DT[c][n] = D[n][c], c<455, n<512 ----------------
__global__ void transpose_D(const float* __restrict__ D, short* __restrict__ DT) {
    int idx = blockIdx.x * 256 + threadIdx.x;
    if (idx >= 455 * 512) return;
    int n = idx & 511, c = idx >> 9;
    DT[(size_t)c * 512 + n] = f2bf(D[(size_t)n * 455 + c]);
}

// ---------------- x packing: XP2[(b*d+i)][f*d+u] = bf16(x[b,f,off+u*d+i]) ----------------
// Block = (f-chunk of 64, b). Coalesced reads (runs of sz floats), LDS transpose,
// coalesced writes (runs of 64*d shorts).
template <int d>
__global__ __launch_bounds__(256) void pack_x(const float* __restrict__ x,
                                              short* __restrict__ XP, int off) {
    constexpr int sz = d * d;
    constexpr int K = 128 * d;
    const int fc = blockIdx.x, b = blockIdx.y;
    __shared__ short Ls[64][sz + 1];
    const int tid = threadIdx.x;
    const float* xb = x + ((size_t)b * 128 + fc * 64) * 455 + off;
    for (int e = tid; e < 64 * sz; e += 256) {
        int ff = e / sz, t = e - ff * sz;
        Ls[ff][t] = f2bf(xb[(size_t)ff * 455 + t]);
    }
    __syncthreads();
    for (int e = tid; e < 64 * sz; e += 256) {
        int i = e / (64 * d);
        int rem = e - i * (64 * d);
        int ff = rem / d, u = rem - ff * d;
        XP[((size_t)b * d + i) * K + (fc * 64 + ff) * d + u] = Ls[ff][u * d + i];
    }
}

// ---------------- Phase 1 fallback: per-l GEMM M=16384(fg), N=d^2(c), K=512 ----------------
template <int d>
__global__ __launch_bounds__(256) void psi_gemm(const float* __restrict__ w,
                                                const short* __restrict__ DT,
                                                short* __restrict__ PSI, int off) {
    constexpr int sz = d * d;
    constexpr int KP = 128 * d;
    const int mt = blockIdx.x;
    const int nt = blockIdx.y;
    const int tid = threadIdx.x, wave = tid >> 6, lane = tid & 63;
    const int wm = (wave & 1) * 32, wn = (wave >> 1) * 64;

    __shared__ short As[64][72];
    __shared__ short Bs[128][72];

    const float* Ag = w + (size_t)(mt * 64) * 512;
    f32x4 acc[2][4] = {};

    for (int k0 = 0; k0 < 512; k0 += 64) {
        __syncthreads();
#pragma unroll
        for (int c = 0; c < 4; ++c) {
            int e = (tid + c * 256) * 4;
            int r = e >> 6, cc = e & 63;
            float4 v = *reinterpret_cast<const float4*>(Ag + (size_t)r * 512 + k0 + cc);
            short4v s;
            s.x = f2bf(v.x); s.y = f2bf(v.y); s.z = f2bf(v.z); s.w = f2bf(v.w);
            *reinterpret_cast<short4v*>(&As[r][cc]) = s;
        }
#pragma unroll
        for (int c = 0; c < 4; ++c) {
            int ch = tid + c * 256;
            int r = ch >> 3, cc = (ch & 7) * 8;
            int gc = nt * 128 + r;
            int row = off + (gc < sz ? gc : 0);
            short8 v = *reinterpret_cast<const short8*>(DT + (size_t)row * 512 + k0 + cc);
            *reinterpret_cast<short8*>(&Bs[r][cc]) = v;
        }
        __syncthreads();
#pragma unroll
        for (int kf = 0; kf < 2; ++kf) {
            const int kc = kf * 32 + (lane >> 4) * 8;
            short8 af[2], bfr[4];
#pragma unroll
            for (int mi = 0; mi < 2; ++mi)
                af[mi] = *reinterpret_cast<const short8*>(&As[wm + mi * 16 + (lane & 15)][kc]);
#pragma unroll
            for (int ni = 0; ni < 4; ++ni)
                bfr[ni] = *reinterpret_cast<const short8*>(&Bs[wn + ni * 16 + (lane & 15)][kc]);
#pragma unroll
            for (int mi = 0; mi < 2; ++mi)
#pragma unroll
                for (int ni = 0; ni < 4; ++ni)
                    acc[mi][ni] = __builtin_amdgcn_mfma_f32_16x16x32_bf16(
                        as_bf8(af[mi]), as_bf8(bfr[ni]), acc[mi][ni], 0, 0, 0);
        }
    }

    const float s1 = 0.044194173824159216f;  // 1/sqrt(512)
#pragma unroll
    for (int mi = 0; mi < 2; ++mi)
#pragma unroll
        for (int ni = 0; ni < 4; ++ni) {
            int cix = nt * 128 + wn + ni * 16 + (lane & 15);
            if (cix < sz) {
                int u = cix / d, v = cix - u * d;
#pragma unroll
                for (int r = 0; r < 4; ++r) {
                    int m = mt * 64 + wm + mi * 16 + (lane >> 4) * 4 + r;
                    int f = m >> 7, g = m & 127;
                    PSI[(size_t)(g * d + v) * KP + f * d + u] = f2bf(acc[mi][ni][r] * s1);
                }
            }
        }
}

// ---------------- Phase 1 fused: one GEMM over all l. M=16384, N=512(+pad), K=512 ----------
// Column cp maps to (l, v, u) with u fastest: cp = OFFS[l] + v*d + u. B row = DT[off+u*d+v].
// Dest PSI_T[l][(g*d+v)][f*d+u] -> lane-fast u gives contiguous 2d-byte store runs.
__global__ __launch_bounds__(256) void psi_gemm_all(const float* __restrict__ w,
                                                    const short* __restrict__ DT,
                                                    short* __restrict__ PSIall) {
    int id = blockIdx.y * gridDim.x + blockIdx.x;      // grid (4,256) -> 0..1023
    id = (id & 7) * 128 + (id >> 3);                   // chunked XCD swizzle (1024%8==0)
    const int nt = id & 3, mt = id >> 2;
    const int tid = threadIdx.x, wave = tid >> 6, lane = tid & 63;
    const int wm = (wave & 1) * 32, wn = (wave >> 1) * 64;

    __shared__ short As[64][72];
    __shared__ short Bs[128][72];
    __shared__ int colInfo[128];

    if (tid < 128) {
        int cp = nt * 128 + tid;
        int info = -1;
        if (cp < 455) {
            int l = 6;
            while (OFFS_D[l] > cp) --l;
            int t = cp - OFFS_D[l];
            int d = 2 * l + 1;
            int v = t / d, u = t - v * d;
            info = (OFFS_D[l] + u * d + v) | (u << 9) | (v << 13) | (l << 17);
        }
        colInfo[tid] = info;
    }
    __syncthreads();

    int brow[4];
#pragma unroll
    for (int c = 0; c < 4; ++c) {
        int inf = colInfo[(tid + c * 256) >> 3];
        brow[c] = (inf < 0) ? 0 : (inf & 511);
    }

    const float* Ag = w + (size_t)(mt * 64) * 512;
    f32x4 acc[2][4] = {};

    for (int k0 = 0; k0 < 512; k0 += 64) {
        __syncthreads();
#pragma unroll
        for (int c = 0; c < 4; ++c) {
            int e = (tid + c * 256) * 4;
            int r = e >> 6, cc = e & 63;
            float4 v = *reinterpret_cast<const float4*>(Ag + (size_t)r * 512 + k0 + cc);
            short4v s;
            s.x = f2bf(v.x); s.y = f2bf(v.y); s.z = f2bf(v.z); s.w = f2bf(v.w);
            *reinterpret_cast<short4v*>(&As[r][cc]) = s;
        }
#pragma unroll
        for (int c = 0; c < 4; ++c) {
            int ch = tid + c * 256;
            int r = ch >> 3, cc = (ch & 7) * 8;
            short8 v = *reinterpret_cast<const short8*>(DT + (size_t)brow[c] * 512 + k0 + cc);
            *reinterpret_cast<short8*>(&Bs[r][cc]) = v;
        }
        __syncthreads();
#pragma unroll
        for (int kf = 0; kf < 2; ++kf) {
            const int kc = kf * 32 + (lane >> 4) * 8;
            short8 af[2], bfr[4];
#pragma unroll
            for (int mi = 0; mi < 2; ++mi)
                af[mi] = *reinterpret_cast<const short8*>(&As[wm + mi * 16 + (lane & 15)][kc]);
#pragma unroll
            for (int ni = 0; ni < 4; ++ni)
                bfr[ni] = *reinterpret_cast<const short8*>(&Bs[wn + ni * 16 + (lane & 15)][kc]);
#pragma unroll
            for (int mi = 0; mi < 2; ++mi)
#pragma unroll
                for (int ni = 0; ni < 4; ++ni)
                    acc[mi][ni] = __builtin_amdgcn_mfma_f32_16x16x32_bf16(
                        as_bf8(af[mi]), as_bf8(bfr[ni]), acc[mi][ni], 0, 0, 0);
        }
    }

    const float s1 = 0.044194173824159216f;  // 1/sqrt(512)
    const int f = mt >> 1;                   // uniform per block (64-row tile in 128-row f-band)
#pragma unroll
    for (int mi = 0; mi < 2; ++mi)
#pragma unroll
        for (int ni = 0; ni < 4; ++ni) {
            int inf = colInfo[wn + ni * 16 + (lane & 15)];
            if (inf >= 0) {
                int u = (inf >> 9) & 15, v = (inf >> 13) & 15, l = (inf >> 17) & 7;
                int d = 2 * l + 1;
                size_t base = PSIOFF_D[l];
#pragma unroll
                for (int r = 0; r < 4; ++r) {
                    int m = mt * 64 + wm + mi * 16 + (lane >> 4) * 4 + r;
                    int g = m & 127;
                    PSIall[base + (size_t)(g * d + v) * (128 * d) + f * d + u] =
                        f2bf(acc[mi][ni][r] * s1);
                }
            }
        }
}

// ---------------- Phase 2: operand-swapped GEMM, M=128d (g,v), N=256d (b,i), K=128d -------
template <int d>
__global__ __launch_bounds__(256) void so3_gemm(const short* __restrict__ XP,
                                                const short* __restrict__ PSI,
                                                float* __restrict__ out, int off) {
    constexpr int K = 128 * d;
    constexpr int GX = 2 * d;
    constexpr int NWG = 4 * d * d;
    int id = blockIdx.y * gridDim.x + blockIdx.x;
    {   // bijective chunked XCD swizzle (m204 variant; NWG%8==4 always for odd d)
        constexpr int q = NWG >> 3, rr = NWG & 7;
        int xcd = id & 7, pos = id >> 3;
        id = (xcd < rr ? xcd * (q + 1) : rr * (q + 1) + (xcd - rr) * q) + pos;
    }
    const int mt = id % GX, nt = id / GX;
    const int tid = threadIdx.x, wave = tid >> 6, lane = tid & 63;
    const int wm = (wave & 1) * 32, wn = (wave >> 1) * 64;

    __shared__ short As[64][72];
    __shared__ short Bs[128][72];

    const short* Ag = PSI + (size_t)(mt * 64) * K;    // A rows = PSI_T rows (g*d+v)
    const short* Bg = XP + (size_t)(nt * 128) * K;    // B rows = XP2 rows (b*d+i)
    f32x4 acc[2][4] = {};

    for (int k0 = 0; k0 < K; k0 += 64) {
        __syncthreads();
#pragma unroll
        for (int c = 0; c < 2; ++c) {     // A: 512 chunks of 16B
            int ch = tid + c * 256;
            int r = ch >> 3, cc = (ch & 7) * 8;
            *reinterpret_cast<short8*>(&As[r][cc]) =
                *reinterpret_cast<const short8*>(Ag + (size_t)r * K + k0 + cc);
        }
#pragma unroll
        for (int c = 0; c < 4; ++c) {     // B: 1024 chunks of 16B
            int ch = tid + c * 256;
            int r = ch >> 3, cc = (ch & 7) * 8;
            *reinterpret_cast<short8*>(&Bs[r][cc]) =
                *reinterpret_cast<const short8*>(Bg + (size_t)r * K + k0 + cc);
        }
        __syncthreads();
#pragma unroll
        for (int kf = 0; kf < 2; ++kf) {
            const int kc = kf * 32 + (lane >> 4) * 8;
            short8 af[2], bfr[4];
#pragma unroll
            for (int mi = 0; mi < 2; ++mi)
                af[mi] = *reinterpret_cast<const short8*>(&As[wm + mi * 16 + (lane & 15)][kc]);
#pragma unroll
            for (int ni = 0; ni < 4; ++ni)
                bfr[ni] = *reinterpret_cast<const short8*>(&Bs[wn + ni * 16 + (lane & 15)][kc]);
#pragma unroll
            for (int mi = 0; mi < 2; ++mi)
#pragma unroll
                for (int ni = 0; ni < 4; ++ni)
                    acc[mi][ni] = __builtin_amdgcn_mfma_f32_16x16x32_bf16(
                        as_bf8(af[mi]), as_bf8(bfr[ni]), acc[mi][ni], 0, 0, 0);
        }
    }

    const float s2 = rsqrtf(128.0f * (float)d);
#pragma unroll
    for (int mi = 0; mi < 2; ++mi)
#pragma unroll
        for (int ni = 0; ni < 4; ++ni) {
            int n = nt * 128 + wn + ni * 16 + (lane & 15);
            int b = n / d, i = n - b * d;          // lane-fast = i -> contiguous d-runs
#pragma unroll
            for (int r = 0; r < 4; ++r) {
                int m = mt * 64 + wm + mi * 16 + (lane >> 4) * 4 + r;
                int g = m / d, v = m - g * d;
                out[((size_t)b * 128 + g) * 455 + off + v * d + i] = acc[mi][ni][r] * s2;
            }
        }
}

// ---------------- per-l driver ----------------
template <int l>
static void run_l(const float* x, const float* w, const short* DT, short* PSIbase,
                  short* XP, float* out, bool fused, hipStream_t stream) {
    constexpr int d = 2 * l + 1;
    const int off = OFFS_H[l];
    if (!fused) {
        constexpr int sz = d * d;
        constexpr int ntiles = (sz + 127) / 128;
        psi_gemm<d><<<dim3(256, ntiles), 256, 0, stream>>>(w, DT, PSIbase, off);
    }
    pack_x<d><<<dim3(2, 256), 256, 0, stream>>>(x, XP, off);
    const short* P = fused ? (PSIbase + PSIOFF_H[l]) : PSIbase;
    so3_gemm<d><<<dim3(2 * d, 2 * d), 256, 0, stream>>>(XP, P, out, off);
}

extern "C" void kernel_launch(void* const* d_in, const int* in_sizes, int n_in,
                              void* d_out, int out_size, void* d_ws, size_t ws_size,
                              hipStream_t stream) {
    const float* x = (const float*)d_in[0];   // [256,128,455]
    const float* w = (const float*)d_in[1];   // [128,128,512]
    const float* D = (const float*)d_in[2];   // [512,455]
    float* out = (float*)d_out;

    char* ws = (char*)d_ws;
    const size_t dtBytes     = (size_t)455 * 512 * 2;       //    465,920
    const size_t psiAllBytes = (size_t)7454720 * 2;         // 14,909,440 (all-l PSI)
    const size_t psiSlotBytes = (size_t)1664 * 1664 * 2;    //  5,537,792 (l=6 slot)
    const size_t xpBytes     = (size_t)3328 * 1664 * 2;     // 11,067,392 (l=6 XP2)

    const bool fused = ws_size >= dtBytes + psiAllBytes + xpBytes;  // 26.44 MB
    short* DT  = (short*)ws;
    short* PSIbase = (short*)(ws + dtBytes);
    short* XP  = (short*)(ws + dtBytes + (fused ? psiAllBytes : psiSlotBytes));

    transpose_D<<<(455 * 512 + 255) / 256, 256, 0, stream>>>(D, DT);
    if (fused)
        psi_gemm_all<<<dim3(4, 256), 256, 0, stream>>>(w, DT, PSIbase);

    run_l<0>(x, w, DT, PSIbase, XP, out, fused, stream);
    run_l<1>(x, w, DT, PSIbase, XP, out, fused, stream);
    run_l<2>(x, w, DT, PSIbase, XP, out, fused, stream);
    run_l<3>(x, w, DT, PSIbase, XP, out, fused, stream);
    run_l<4>(x, w, DT, PSIbase, XP, out, fused, stream);
    run_l<5>(x, w, DT, PSIbase, XP, out, fused, stream);
    run_l<6>(x, w, DT, PSIbase, XP, out, fused, stream);
}